// Round 4
// baseline (719.654 us; speedup 1.0000x reference)
//
#include <hip/hip_runtime.h>

#define IMG   256
#define NPIX  65536          // 256*256
#define PH    63             // patches per side
#define NNODE 3969           // PH*PH
#define SN    4000           // padded node stride (mult of 32, 16B-aligned rows)
#define SN2   4096           // g1n/a1t row count (margin for 128-node tiles)
#define HID   64
#define GH    128
#define BATCH 4

typedef __attribute__((ext_vector_type(8))) short short8;
typedef __attribute__((ext_vector_type(4))) float float4v;
typedef unsigned short ushort_t;

__device__ inline ushort_t f2bf(float f) {
    union { float f; unsigned u; } v; v.f = f;
    unsigned r = v.u + 0x7FFF + ((v.u >> 16) & 1);   // RNE
    return (ushort_t)(r >> 16);
}
__device__ inline unsigned pk2(float a, float b) {
    return (unsigned)f2bf(a) | ((unsigned)f2bf(b) << 16);
}

// ---------------------------------------------------------------------------
// adj fp32 [b][N][N] -> bf16 [b][N][SN], K-pad (3969..3999) zeroed
// ---------------------------------------------------------------------------
__global__ __launch_bounds__(256) void k_cvt_adj(const float* __restrict__ adj,
                                                 ushort_t* __restrict__ adjb) {
    int n = blockIdx.x, b = blockIdx.y;
    const float* src = adj + (size_t)(b * NNODE + n) * NNODE;
    unsigned* dst = (unsigned*)(adjb + (size_t)(b * NNODE + n) * SN);
    for (int c2 = threadIdx.x; c2 < SN / 2; c2 += 256) {
        int c = c2 * 2;
        float f0 = (c < NNODE) ? src[c] : 0.f;
        float f1 = (c + 1 < NNODE) ? src[c + 1] : 0.f;
        dst[c2] = pk2(f0, f1);
    }
}

// ---------------------------------------------------------------------------
// prepack: W2p[tap][oc][ic] (conv2), w3p[g][pix], w4p[g][k]  (all bf16)
// ---------------------------------------------------------------------------
__global__ __launch_bounds__(256) void k_prepack(const float* __restrict__ cw2,
                                                 const float* __restrict__ w3,
                                                 const float* __restrict__ w4,
                                                 ushort_t* __restrict__ W2p,
                                                 ushort_t* __restrict__ w3p,
                                                 ushort_t* __restrict__ w4p) {
    int idx = blockIdx.x * 256 + threadIdx.x;   // 36864 + 8192 + 8192 = 53248
    if (idx < 36864) {
        int tap = idx >> 12, rem = idx & 4095;
        int oc = rem >> 6, ic = rem & 63;
        W2p[idx] = f2bf(cw2[(oc * 64 + ic) * 9 + tap]);
    } else if (idx < 45056) {
        int i2 = idx - 36864;                   // w3p[g][pix] = w3[pix][g]
        int g = i2 >> 6, pix = i2 & 63;
        w3p[i2] = f2bf(w3[pix * GH + g]);
    } else if (idx < 53248) {
        int i3 = idx - 45056;                   // w4p[g][k] = w4[k][g]
        int g = i3 >> 7, k = i3 & 127;
        w4p[i3] = f2bf(w4[k * 64 + g]);
    }
}

// ---------------------------------------------------------------------------
// sup1T[b][g][n] = sum_pix w3p[g][pix] * patch[n][pix]  (MFMA, bf16 out)
// Block: 128 g x 128 n; waves 2x2 of 64x64; K=64 pix in 2 chunks of 32.
// ---------------------------------------------------------------------------
__global__ __launch_bounds__(256) void k_sup1(const float* __restrict__ in,
                                              const ushort_t* __restrict__ w3p,
                                              ushort_t* __restrict__ sup1T) {
    __shared__ ushort_t Ps[128][72];            // 18.4 KB, stride 144B
    const int b = blockIdx.z;
    const int n0 = blockIdx.x * 128;
    const float* inb = in + (size_t)b * NPIX;
    const int t = threadIdx.x;
    const int lane = t & 63, w = t >> 6;
    const int l15 = lane & 15, q = lane >> 4;

    // stage 128 patches (8 rows of 8 px each), vectorized float4 reads
    for (int idx = t; idx < 1024; idx += 256) {
        int nl = idx >> 3, i = idx & 7;
        int n = n0 + nl;
        unsigned pk[4] = {0u, 0u, 0u, 0u};
        if (n < NNODE) {
            int py = n / PH, px = n - py * PH;
            const float* rp = inb + (py * 4 + i) * IMG + px * 4;
            float4 a = *(const float4*)rp;
            float4 c = *(const float4*)(rp + 4);
            pk[0] = pk2(a.x, a.y); pk[1] = pk2(a.z, a.w);
            pk[2] = pk2(c.x, c.y); pk[3] = pk2(c.z, c.w);
        }
        *(uint4*)&Ps[nl][i * 8] = *(uint4*)pk;
    }
    __syncthreads();

    const int g0 = (w & 1) * 64, nw = (w >> 1) * 64;
    float4v acc[4][4];
#pragma unroll
    for (int i = 0; i < 4; ++i)
#pragma unroll
        for (int j = 0; j < 4; ++j)
#pragma unroll
            for (int r = 0; r < 4; ++r) acc[i][j][r] = 0.f;

#pragma unroll
    for (int c = 0; c < 2; ++c) {
        short8 af[4], bf[4];
#pragma unroll
        for (int i = 0; i < 4; ++i)
            af[i] = *(const short8*)&w3p[(g0 + i * 16 + l15) * 64 + c * 32 + q * 8];
#pragma unroll
        for (int j = 0; j < 4; ++j)
            bf[j] = *(const short8*)&Ps[nw + j * 16 + l15][c * 32 + q * 8];
#pragma unroll
        for (int i = 0; i < 4; ++i)
#pragma unroll
            for (int j = 0; j < 4; ++j)
                acc[i][j] = __builtin_amdgcn_mfma_f32_16x16x32_bf16(
                    af[i], bf[j], acc[i][j], 0, 0, 0);
    }
    // D: col(n)=lane&15, row(g)=q*4+r. Pad n in [NNODE,SN) gets exact 0.
    ushort_t* dst = sup1T + (size_t)b * GH * SN;
#pragma unroll
    for (int i = 0; i < 4; ++i)
#pragma unroll
        for (int j = 0; j < 4; ++j) {
            int n = n0 + nw + j * 16 + l15;
            if (n < SN) {
                int g = g0 + i * 16 + q * 4;
#pragma unroll
                for (int r = 0; r < 4; ++r)
                    dst[(size_t)(g + r) * SN + n] = f2bf(acc[i][j][r]);
            }
        }
}

// ---------------------------------------------------------------------------
// MFMA GEMM: for g,n: sum_k supT[g][k] * adj[n][k], K-split x4 atomics.
// TRANS=1 (G=128): out g1n[n][128] (coalesced 4-float runs per lane).
// TRANS=0 (G=64):  out g2T[g][SN].
// ---------------------------------------------------------------------------
template <int G, bool TRANS>
__global__ __launch_bounds__(256) void k_gemm_mfma(const ushort_t* __restrict__ adjb,
                                                   const ushort_t* __restrict__ supT,
                                                   float* __restrict__ C) {
    constexpr int FN = (G == 128) ? 4 : 2;
    const int b = blockIdx.z, ks = blockIdx.y;
    const int node0 = blockIdx.x * 128;
    const int t = threadIdx.x;
    const int lane = t & 63, w = t >> 6;
    const int l15 = lane & 15, q = lane >> 4;
    const int wm0 = (G == 128) ? (w & 1) * 64 : 0;
    const int wn0 = (G == 128) ? (w >> 1) * 64 : w * 32;

    __shared__ ushort_t Als[G][40];
    __shared__ ushort_t Bls[128][40];

    const int k0c = ks * 992;
    const int kend = (ks == 3) ? NNODE : k0c + 992;
    const int kiters = (kend - k0c + 31) >> 5;

    const ushort_t* Ab = supT + (size_t)b * G * SN;
    const ushort_t* Bb = adjb + (size_t)b * NNODE * SN;

    float4v acc[4][FN];
#pragma unroll
    for (int i = 0; i < 4; ++i)
#pragma unroll
        for (int j = 0; j < FN; ++j)
#pragma unroll
            for (int r = 0; r < 4; ++r) acc[i][j][r] = 0.f;

    for (int kk = 0; kk < kiters; ++kk) {
        const int kbase = k0c + kk * 32;
#pragma unroll
        for (int i = 0; i < G / 64; ++i) {
            int idx = t + i * 256;
            int r = idx >> 2, s = idx & 3;
            *(uint4*)&Als[r][s * 8] =
                *(const uint4*)&Ab[(size_t)r * SN + kbase + s * 8];
        }
        // B rows >= NNODE read in-bounds-of-ws garbage; discarded below.
#pragma unroll
        for (int i = 0; i < 2; ++i) {
            int idx = t + i * 256;
            int r = idx >> 2, s = idx & 3;
            *(uint4*)&Bls[r][s * 8] =
                *(const uint4*)&Bb[(size_t)(node0 + r) * SN + kbase + s * 8];
        }
        __syncthreads();
        short8 af[4], bf[FN];
#pragma unroll
        for (int i = 0; i < 4; ++i)
            af[i] = *(const short8*)&Als[wm0 + i * 16 + l15][q * 8];
#pragma unroll
        for (int j = 0; j < FN; ++j)
            bf[j] = *(const short8*)&Bls[wn0 + j * 16 + l15][q * 8];
#pragma unroll
        for (int i = 0; i < 4; ++i)
#pragma unroll
            for (int j = 0; j < FN; ++j)
                acc[i][j] = __builtin_amdgcn_mfma_f32_16x16x32_bf16(
                    af[i], bf[j], acc[i][j], 0, 0, 0);
        __syncthreads();
    }
    if (TRANS) {
        float* Cb = C + (size_t)b * SN2 * 128;
#pragma unroll
        for (int i = 0; i < 4; ++i) {
            int gg = wm0 + i * 16 + q * 4;
#pragma unroll
            for (int j = 0; j < FN; ++j) {
                int nn = node0 + wn0 + j * 16 + l15;
                if (nn < NNODE) {
#pragma unroll
                    for (int r = 0; r < 4; ++r)
                        unsafeAtomicAdd(&Cb[(size_t)nn * 128 + gg + r], acc[i][j][r]);
                }
            }
        }
    } else {
        float* Cb = C + (size_t)b * G * SN;
#pragma unroll
        for (int i = 0; i < 4; ++i) {
            int gg = wm0 + i * 16 + q * 4;
#pragma unroll
            for (int j = 0; j < FN; ++j) {
                int nn = node0 + wn0 + j * 16 + l15;
                if (nn < NNODE) {
#pragma unroll
                    for (int r = 0; r < 4; ++r)
                        unsafeAtomicAdd(&Cb[(size_t)(gg + r) * SN + nn], acc[i][j][r]);
                }
            }
        }
    }
}

// ---------------------------------------------------------------------------
// a1t[b][n][k] = bf16(relu(g1n[b][n][k] + gb3[k])), fully vectorized
// ---------------------------------------------------------------------------
__global__ __launch_bounds__(256) void k_act(const float* __restrict__ g1n,
                                             const float* __restrict__ gb3,
                                             ushort_t* __restrict__ a1t) {
    int idx = blockIdx.x * 256 + threadIdx.x;   // 4*4096*16 = 262144
    int b = idx >> 16, rem = idx & 65535;
    int n = rem >> 4, kg = rem & 15;
    const float* src = g1n + ((size_t)b * SN2 + n) * 128 + kg * 8;
    float4 a = *(const float4*)src;
    float4 c = *(const float4*)(src + 4);
    float4 ba = *(const float4*)(gb3 + kg * 8);
    float4 bc = *(const float4*)(gb3 + kg * 8 + 4);
    unsigned pk[4];
    pk[0] = pk2(fmaxf(a.x + ba.x, 0.f), fmaxf(a.y + ba.y, 0.f));
    pk[1] = pk2(fmaxf(a.z + ba.z, 0.f), fmaxf(a.w + ba.w, 0.f));
    pk[2] = pk2(fmaxf(c.x + bc.x, 0.f), fmaxf(c.y + bc.y, 0.f));
    pk[3] = pk2(fmaxf(c.z + bc.z, 0.f), fmaxf(c.w + bc.w, 0.f));
    *(uint4*)(a1t + ((size_t)b * SN2 + n) * 128 + kg * 8) = *(uint4*)pk;
}

// ---------------------------------------------------------------------------
// sup2T[b][g][n] = sum_k w4p[g][k] * a1t[n][k]  (MFMA, K=128, single stage)
// Block: 64 g x 128 n; 4 waves of 64g x 32n; 4 K-chunks.
// ---------------------------------------------------------------------------
__global__ __launch_bounds__(256) void k_gemm_s2(const ushort_t* __restrict__ a1t,
                                                 const ushort_t* __restrict__ w4p,
                                                 ushort_t* __restrict__ sup2T) {
    __shared__ ushort_t Ls[128][136];           // 34.8 KB
    const int b = blockIdx.y;
    const int n0 = blockIdx.x * 128;
    const int t = threadIdx.x;
    const int lane = t & 63, w = t >> 6;
    const int l15 = lane & 15, q = lane >> 4;

    const ushort_t* src = a1t + (size_t)b * SN2 * 128;
    for (int idx = t; idx < 2048; idx += 256) {
        int nl = idx >> 4, kg = idx & 15;
        *(uint4*)&Ls[nl][kg * 8] =
            *(const uint4*)&src[(size_t)(n0 + nl) * 128 + kg * 8];
    }
    __syncthreads();

    const int nw = w * 32;
    float4v acc[4][2];
#pragma unroll
    for (int i = 0; i < 4; ++i)
#pragma unroll
        for (int j = 0; j < 2; ++j)
#pragma unroll
            for (int r = 0; r < 4; ++r) acc[i][j][r] = 0.f;

#pragma unroll
    for (int c = 0; c < 4; ++c) {
        short8 af[4], bf[2];
#pragma unroll
        for (int i = 0; i < 4; ++i)
            af[i] = *(const short8*)&w4p[(i * 16 + l15) * 128 + c * 32 + q * 8];
#pragma unroll
        for (int j = 0; j < 2; ++j)
            bf[j] = *(const short8*)&Ls[nw + j * 16 + l15][c * 32 + q * 8];
#pragma unroll
        for (int i = 0; i < 4; ++i)
#pragma unroll
            for (int j = 0; j < 2; ++j)
                acc[i][j] = __builtin_amdgcn_mfma_f32_16x16x32_bf16(
                    af[i], bf[j], acc[i][j], 0, 0, 0);
    }
    ushort_t* dst = sup2T + (size_t)b * 64 * SN;
#pragma unroll
    for (int i = 0; i < 4; ++i)
#pragma unroll
        for (int j = 0; j < 2; ++j) {
            int n = n0 + nw + j * 16 + l15;
            if (n < SN) {
                int g = i * 16 + q * 4;
#pragma unroll
                for (int r = 0; r < 4; ++r)
                    dst[(size_t)(g + r) * SN + n] = f2bf(acc[i][j][r]);
            }
        }
}

// ---------------------------------------------------------------------------
// conv1: 1 -> 64 ch, 3x3 SAME, relu. Output NHWC bf16: h1n[b][pix][64]
// ---------------------------------------------------------------------------
__global__ __launch_bounds__(256) void k_conv1(const float* __restrict__ in,
                                               const float* __restrict__ w,
                                               const float* __restrict__ bias,
                                               ushort_t* __restrict__ h1n) {
    int b = blockIdx.z;
    const float* inb = in + (size_t)b * NPIX;
    __shared__ float s[18][18];
    __shared__ float ws[576];
    int tx = threadIdx.x & 15, ty = threadIdx.x >> 4;
    int x0 = blockIdx.x * 16, y0 = blockIdx.y * 16;
    for (int idx = threadIdx.x; idx < 324; idx += 256) {
        int yy = idx / 18, xx = idx - yy * 18;
        int gy = y0 + yy - 1, gx = x0 + xx - 1;
        s[yy][xx] = (gy >= 0 && gy < IMG && gx >= 0 && gx < IMG) ? inb[gy * IMG + gx] : 0.f;
    }
    for (int idx = threadIdx.x; idx < 576; idx += 256) ws[idx] = w[idx];
    __syncthreads();
    float r[9];
#pragma unroll
    for (int dy = 0; dy < 3; ++dy)
#pragma unroll
        for (int dx = 0; dx < 3; ++dx) r[dy * 3 + dx] = s[ty + dy][tx + dx];
    int outp = (y0 + ty) * IMG + x0 + tx;
    ushort_t* dst = h1n + ((size_t)b * NPIX + outp) * 64;
#pragma unroll
    for (int sgrp = 0; sgrp < 8; ++sgrp) {
        unsigned pk[4];
#pragma unroll
        for (int h = 0; h < 4; ++h) {
            int oc0 = sgrp * 8 + h * 2;
            float a0 = bias[oc0], a1 = bias[oc0 + 1];
#pragma unroll
            for (int k = 0; k < 9; ++k) {
                a0 += r[k] * ws[oc0 * 9 + k];
                a1 += r[k] * ws[(oc0 + 1) * 9 + k];
            }
            pk[h] = pk2(fmaxf(a0, 0.f), fmaxf(a1, 0.f));
        }
        *(uint4*)&dst[sgrp * 8] = *(uint4*)pk;
    }
}

// ---------------------------------------------------------------------------
// conv2 implicit-GEMM MFMA: 64oc x (32x8 pixel tile), K = 9 taps x 64 ic.
// ---------------------------------------------------------------------------
__global__ __launch_bounds__(256) void k_conv2(const ushort_t* __restrict__ h1n,
                                               const ushort_t* __restrict__ W2p,
                                               const float* __restrict__ bias,
                                               float* __restrict__ h2) {
    __shared__ ushort_t Xs[340 * 72];           // 48,960 B
    const int b = blockIdx.z;
    const ushort_t* h1b = h1n + (size_t)b * NPIX * 64;
    float* h2b = h2 + (size_t)b * 64 * NPIX;
    const int t = threadIdx.x;
    const int lane = t & 63, w = t >> 6;
    const int l15 = lane & 15, q = lane >> 4;
    const int x0 = blockIdx.x * 32, y0 = blockIdx.y * 8;

    for (int idx = t; idx < 2720; idx += 256) {
        int hp = idx >> 3, s = idx & 7;
        int hy = hp / 34, hx = hp - hy * 34;
        int gy = y0 + hy - 1, gx = x0 + hx - 1;
        uint4 v = {0u, 0u, 0u, 0u};
        if (gy >= 0 && gy < IMG && gx >= 0 && gx < IMG)
            v = *(const uint4*)&h1b[((size_t)gy * IMG + gx) * 64 + s * 8];
        *(uint4*)&Xs[hp * 72 + s * 8] = v;
    }
    __syncthreads();

    const int wn0 = w * 64;
    int pbase[4];
#pragma unroll
    for (int j = 0; j < 4; ++j) {
        int p = wn0 + j * 16 + l15;
        pbase[j] = (p >> 5) * 34 + (p & 31);
    }

    float4v acc[4][4];
#pragma unroll
    for (int i = 0; i < 4; ++i)
#pragma unroll
        for (int j = 0; j < 4; ++j)
#pragma unroll
            for (int r = 0; r < 4; ++r) acc[i][j][r] = 0.f;

    for (int tap = 0; tap < 9; ++tap) {
        int ky = tap / 3, kx = tap - ky * 3;
        const ushort_t* wp = W2p + tap * 4096;
#pragma unroll
        for (int c = 0; c < 2; ++c) {
            short8 af[4], bf[4];
#pragma unroll
            for (int i = 0; i < 4; ++i)
                af[i] = *(const short8*)&wp[(i * 16 + l15) * 64 + c * 32 + q * 8];
#pragma unroll
            for (int j = 0; j < 4; ++j)
                bf[j] = *(const short8*)&Xs[(pbase[j] + ky * 34 + kx) * 72 + c * 32 + q * 8];
#pragma unroll
            for (int i = 0; i < 4; ++i)
#pragma unroll
                for (int j = 0; j < 4; ++j)
                    acc[i][j] = __builtin_amdgcn_mfma_f32_16x16x32_bf16(
                        af[i], bf[j], acc[i][j], 0, 0, 0);
        }
    }
#pragma unroll
    for (int i = 0; i < 4; ++i) {
#pragma unroll
        for (int j = 0; j < 4; ++j) {
            int p = wn0 + j * 16 + l15;
            int y = y0 + (p >> 5), x = x0 + (p & 31);
#pragma unroll
            for (int r = 0; r < 4; ++r) {
                int oc = i * 16 + q * 4 + r;
                h2b[(size_t)oc * NPIX + (size_t)y * IMG + x] =
                    fmaxf(acc[i][j][r] + bias[oc], 0.f);
            }
        }
    }
}

// ---------------------------------------------------------------------------
// combine: out = relu( tmp1 + conv3(h2) + gather(g2T + gb4)/cnt )
// ---------------------------------------------------------------------------
__global__ __launch_bounds__(256) void k_combine(const float* __restrict__ in,
                                                 const float* __restrict__ proj,
                                                 const float* __restrict__ lamp,
                                                 const float* __restrict__ h2,
                                                 const float* __restrict__ wc,
                                                 const float* __restrict__ bc,
                                                 const float* __restrict__ g2T,
                                                 const float* __restrict__ gb4,
                                                 float* __restrict__ out) {
    int b = blockIdx.z;
    const float* inb = in + (size_t)b * NPIX;
    const float* prb = proj + (size_t)b * NPIX;
    const float* h2b = h2 + (size_t)b * 64 * NPIX;
    const float* g2b = g2T + (size_t)b * 64 * SN;
    __shared__ float s[16][18][18];
    __shared__ float ws[144];
    int tx = threadIdx.x & 15, ty = threadIdx.x >> 4;
    int x0 = blockIdx.x * 16, y0 = blockIdx.y * 16;
    int y = y0 + ty, x = x0 + tx;

    float acc = bc[0];
    for (int icc = 0; icc < 4; ++icc) {
        for (int idx = threadIdx.x; idx < 16 * 324; idx += 256) {
            int ic = idx / 324, rem = idx - ic * 324;
            int yy = rem / 18, xx = rem - yy * 18;
            int gy = y0 + yy - 1, gx = x0 + xx - 1;
            s[ic][yy][xx] = (gy >= 0 && gy < IMG && gx >= 0 && gx < IMG)
                                ? h2b[(icc * 16 + ic) * NPIX + gy * IMG + gx]
                                : 0.f;
        }
        for (int idx = threadIdx.x; idx < 144; idx += 256) ws[idx] = wc[icc * 144 + idx];
        __syncthreads();
#pragma unroll 4
        for (int ic = 0; ic < 16; ++ic) {
#pragma unroll
            for (int ky = 0; ky < 3; ++ky)
#pragma unroll
                for (int kx = 0; kx < 3; ++kx)
                    acc += s[ic][ty + ky][tx + kx] * ws[ic * 9 + ky * 3 + kx];
        }
        __syncthreads();
    }

    float iv = inb[y * IMG + x], pv = prb[y * IMG + x];
    float tmp1 = iv + lamp[0] * (pv - iv);

    int pylo = (y >= 4) ? ((y - 4) >> 2) : 0;
    int pyhi = min(62, y >> 2);
    int pxlo = (x >= 4) ? ((x - 4) >> 2) : 0;
    int pxhi = min(62, x >> 2);
    float sum = 0.f;
    int cnt = 0;
    for (int py = pylo; py <= pyhi; ++py)
        for (int px = pxlo; px <= pxhi; ++px) {
            int pix = (y - 4 * py) * 8 + (x - 4 * px);
            sum += g2b[(size_t)pix * SN + (py * PH + px)] + gb4[pix];
            ++cnt;
        }
    float tmp3 = sum / (float)cnt;

    out[(size_t)b * NPIX + y * IMG + x] = fmaxf(tmp1 + acc + tmp3, 0.f);
}

// ---------------------------------------------------------------------------
extern "C" void kernel_launch(void* const* d_in, const int* in_sizes, int n_in,
                              void* d_out, int out_size, void* d_ws, size_t ws_size,
                              hipStream_t stream) {
    const float* input = (const float*)d_in[0];
    const float* proj  = (const float*)d_in[1];
    const float* adj   = (const float*)d_in[2];
    const float* lam   = (const float*)d_in[3];
    const float* cw1   = (const float*)d_in[4];
    const float* cb1   = (const float*)d_in[5];
    const float* cw2   = (const float*)d_in[6];
    const float* cb2   = (const float*)d_in[7];
    const float* cw3   = (const float*)d_in[8];
    const float* cb3   = (const float*)d_in[9];
    const float* gw3   = (const float*)d_in[10];
    const float* gb3   = (const float*)d_in[11];
    const float* gw4   = (const float*)d_in[12];
    const float* gb4   = (const float*)d_in[13];
    float* out = (float*)d_out;

    // ws layout (bytes, all regions disjoint, ~251 MB total):
    char* base = (char*)d_ws;
    float*    g2T   = (float*)(base);                 //   4,096,000
    ushort_t* adjb  = (ushort_t*)(base + 4096000);    // 127,008,000 (+1MB OOB-read margin into sup1T)
    ushort_t* sup1T = (ushort_t*)(base + 131104000);  //   4,096,000
    float*    g1n   = (float*)(base + 135200000);     //   8,388,608  [b][SN2][128]
    ushort_t* a1t   = (ushort_t*)(base + 143588608);  //   4,194,304  [b][SN2][128]
    ushort_t* sup2T = (ushort_t*)(base + 147782912);  //   2,048,000
    ushort_t* w3p   = (ushort_t*)(base + 149830912);  //      16,384
    ushort_t* w4p   = (ushort_t*)(base + 149847296);  //      16,384
    ushort_t* W2p   = (ushort_t*)(base + 149863680);  //      73,728
    ushort_t* h1n   = (ushort_t*)(base + 149937408);  //  33,554,432
    float*    h2    = (float*)(base + 183491840);     //  67,108,864

    dim3 blk(256);

    hipMemsetAsync(g1n, 0, (size_t)BATCH * SN2 * 128 * 4, stream);
    hipMemsetAsync(g2T, 0, (size_t)BATCH * 64 * SN * 4, stream);

    k_prepack<<<dim3(208), blk, 0, stream>>>(cw2, gw3, gw4, W2p, w3p, w4p);
    k_cvt_adj<<<dim3(NNODE, BATCH), blk, 0, stream>>>(adj, adjb);

    // GCN branch
    k_sup1<<<dim3(32, 1, BATCH), blk, 0, stream>>>(input, w3p, sup1T);
    k_gemm_mfma<128, true><<<dim3(32, 4, BATCH), blk, 0, stream>>>(adjb, sup1T, g1n);
    k_act<<<dim3(1024), blk, 0, stream>>>(g1n, gb3, a1t);
    k_gemm_s2<<<dim3(32, BATCH), blk, 0, stream>>>(a1t, w4p, sup2T);
    k_gemm_mfma<64, false><<<dim3(32, 4, BATCH), blk, 0, stream>>>(adjb, sup2T, g2T);

    // CNN branch + combine
    k_conv1<<<dim3(16, 16, BATCH), blk, 0, stream>>>(input, cw1, cb1, h1n);
    k_conv2<<<dim3(8, 32, BATCH), blk, 0, stream>>>(h1n, W2p, cb2, h2);
    k_combine<<<dim3(16, 16, BATCH), blk, 0, stream>>>(
        input, proj, lam, h2, cw3, cb3, g2T, gb4, out);
}